// Round 9
// baseline (417.560 us; speedup 1.0000x reference)
//
#include <hip/hip_runtime.h>
#include <hip/hip_bf16.h>

#define DD 128
#define D3 (DD*DD*DD)      // 2097152
#define NB 8               // batch
#define NV 65536           // points
#define HID 256
#define LAT 128

// bricks: 32x8x4 voxels -> 4 x 16 x 32 = 2048 per batch, 16384 total
#define NBIN 2048
#define NBIN_TOT (NBIN*NB) // 16384

// round-to-nearest-even f32 -> bf16, returned as the (exactly representable) f32 value
__device__ __forceinline__ float rbf(float x) {
    unsigned u = __float_as_uint(x);
    unsigned r = (u + 0x7fffu + ((u >> 16) & 1u)) & 0xFFFF0000u;
    return __uint_as_float(r);
}

// ---------------- SIREN layer body (identical numerics to the per-layer kernels) ---
template<int K, int MODE>
__device__ __forceinline__ void layer_body(
    const float* __restrict__ in, const float* __restrict__ w,
    const float* __restrict__ bias, float* __restrict__ outp,
    float* in_s, float* part, int bid)
{
    const int tid = threadIdx.x;
    for (int i = tid; i < NB * K; i += 256) in_s[i] = rbf(in[i]);
    __syncthreads();

    const int cl = tid & 63;             // column within block (wave-contiguous)
    const int ks = tid >> 6;             // k-slice 0..3 (wave-uniform)
    const int col = bid * 64 + cl;

    float acc[NB];
    #pragma unroll
    for (int b = 0; b < NB; ++b) acc[b] = 0.f;

    const int k0 = ks * (K / 4);
    #pragma unroll 8
    for (int k = k0; k < k0 + K / 4; ++k) {
        float wk = rbf(w[k * HID + col]);          // 256B/wave coalesced
        #pragma unroll
        for (int b = 0; b < NB; ++b) acc[b] = fmaf(in_s[b * K + k], wk, acc[b]);
    }

    float* pp = part + (ks * 64 + cl) * 8;
    #pragma unroll
    for (int b = 0; b < NB; ++b) pp[b] = acc[b];
    __syncthreads();

    #pragma unroll
    for (int u = 0; u < 2; ++u) {
        const int idx = tid * 2 + u;               // 512 outputs per block
        const int c2 = idx >> 3, b = idx & 7;
        const int gcol = bid * 64 + c2;
        float s = (part[(0 * 64 + c2) * 8 + b] + part[(1 * 64 + c2) * 8 + b])
                + (part[(2 * 64 + c2) * 8 + b] + part[(3 * 64 + c2) * 8 + b]);
        float t = rbf(s);
        t = rbf(t + rbf(bias[gcol]));
        if (MODE == 0) {
            t = rbf(30.0f * t);
            t = rbf(sinf(t));
        } else if (MODE == 1) {
            float r = rbf(in_s[b * K + gcol] + t);
            t = rbf(sinf(r));
        }
        outp[b * HID + gcol] = t;
    }
    __syncthreads();   // in_s/part fully consumed before caller reuses
}

// device-scope spin barrier for 4 co-resident blocks (counters zeroed per launch)
__device__ __forceinline__ void grid_bar(unsigned* bar, int idx, unsigned nblk) {
    __syncthreads();
    if (threadIdx.x == 0) {
        __threadfence();                       // publish this block's writes
        atomicAdd(&bar[idx], 1u);
        while (atomicAdd(&bar[idx], 0u) < nblk) {}
    }
    __syncthreads();
    __threadfence();                           // acquire other blocks' writes
}

// -------- fused SIREN MLP: one kernel, 4 blocks, global handoff + spin barrier -----
__global__ __launch_bounds__(256) void k_mlp_fused(
    const float* __restrict__ x,
    const float* __restrict__ w0, const float* __restrict__ b0,
    const float* __restrict__ w1, const float* __restrict__ b1,
    const float* __restrict__ w2, const float* __restrict__ b2,
    const float* __restrict__ w3, const float* __restrict__ b3,
    const float* __restrict__ w4, const float* __restrict__ b4,
    float* __restrict__ hA, float* __restrict__ hB, float* __restrict__ h4out,
    unsigned* bar)
{
    __shared__ float in_s[NB * HID];     // 8 KB
    __shared__ float part[4 * 64 * 8];   // 8 KB
    const int bid = blockIdx.x;
    layer_body<LAT, 0>(x,  w0, b0, hA, in_s, part, bid);  grid_bar(bar, 0, 4);
    layer_body<HID, 1>(hA, w1, b1, hB, in_s, part, bid);  grid_bar(bar, 1, 4);
    layer_body<HID, 1>(hB, w2, b2, hA, in_s, part, bid);  grid_bar(bar, 2, 4);
    layer_body<HID, 1>(hA, w3, b3, hB, in_s, part, bid);  grid_bar(bar, 3, 4);
    layer_body<HID, 2>(hB, w4, b4, h4out, in_s, part, bid);
}

// ------ heads: LDS-staged streaming GEMV. thread = 1 point, full k chain. ----------
// 256 blocks x 256 threads; per stage (8 k-rows): coalesced float4 staging of the
// block's wc slice (24 KB) + wv slice (8 KB), issue-early/write-late (T14).
__global__ __launch_bounds__(256) void k_heads(
    const float* __restrict__ h4,
    const float* __restrict__ wc, const float* __restrict__ bc,
    const float* __restrict__ wv, const float* __restrict__ bv,
    const float* __restrict__ coords0, const float* __restrict__ values0,
    float4* __restrict__ posval)
{
    __shared__ float  hsT[HID * NB];       // [k][b] 8 KB, uniform broadcast reads
    __shared__ float4 wcs4[8 * 192];       // 24 KB: 8 rows x 768 floats
    __shared__ float4 wvs4[8 * 64];        // 8 KB:  8 rows x 256 floats

    const int tid = threadIdx.x;
    const int blk = blockIdx.x;
    const int pt  = blk * 256 + tid;       // this thread's point

    // h4 -> [k][b] layout (tiny, once)
    for (int i = tid; i < NB * HID; i += 256) {
        int k = i >> 3, b = i & 7;
        hsT[k * 8 + b] = h4[b * HID + k];
    }

    const float4* wc4 = reinterpret_cast<const float4*>(wc);
    const float4* wv4 = reinterpret_cast<const float4*>(wv);

    // per-thread stage-load slots (wave-aligned: 64 consecutive float4 per instr)
    size_t wbase[6]; int lwc[6];
    #pragma unroll
    for (int j = 0; j < 6; ++j) {
        int idx = j * 256 + tid;
        int row = idx / 192, col = idx - row * 192;       // 192 float4 per wc row-slice
        wbase[j] = (size_t)row * 49152 + (size_t)blk * 192 + col;   // 49152 f4/row
        lwc[j] = row * 192 + col;
    }
    size_t vbase[2]; int lwv[2];
    #pragma unroll
    for (int j = 0; j < 2; ++j) {
        int idx = j * 256 + tid;
        int row = idx >> 6, col = idx & 63;               // 64 float4 per wv row-slice
        vbase[j] = (size_t)row * 16384 + (size_t)blk * 64 + col;    // 16384 f4/row
        lwv[j] = row * 64 + col;
    }

    float acc[4][8];                       // [x,y,z,val][batch]
    #pragma unroll
    for (int c = 0; c < 4; ++c)
        #pragma unroll
        for (int b = 0; b < NB; ++b) acc[c][b] = 0.f;

    // prologue: issue stage-0 loads
    float4 Rw0, Rw1, Rw2, Rw3, Rw4, Rw5, Rv0, Rv1;
    Rw0 = wc4[wbase[0]]; Rw1 = wc4[wbase[1]]; Rw2 = wc4[wbase[2]];
    Rw3 = wc4[wbase[3]]; Rw4 = wc4[wbase[4]]; Rw5 = wc4[wbase[5]];
    Rv0 = wv4[vbase[0]]; Rv1 = wv4[vbase[1]];

    const float4* h4v = reinterpret_cast<const float4*>(hsT);

    for (int s = 0; s < 32; ++s) {
        __syncthreads();                   // stage s-1 consumers done (also hsT fill)
        wcs4[lwc[0]] = Rw0; wcs4[lwc[1]] = Rw1; wcs4[lwc[2]] = Rw2;
        wcs4[lwc[3]] = Rw3; wcs4[lwc[4]] = Rw4; wcs4[lwc[5]] = Rw5;
        wvs4[lwv[0]] = Rv0; wvs4[lwv[1]] = Rv1;
        if (s < 31) {                      // issue next stage early (hidden under FMAs)
            size_t ow = (size_t)(s + 1) * 8 * 49152;
            size_t ov = (size_t)(s + 1) * 8 * 16384;
            Rw0 = wc4[wbase[0] + ow]; Rw1 = wc4[wbase[1] + ow]; Rw2 = wc4[wbase[2] + ow];
            Rw3 = wc4[wbase[3] + ow]; Rw4 = wc4[wbase[4] + ow]; Rw5 = wc4[wbase[5] + ow];
            Rv0 = wv4[vbase[0] + ov]; Rv1 = wv4[vbase[1] + ov];
        }
        __syncthreads();                   // stage s staged

        const float* wcsF = reinterpret_cast<const float*>(wcs4);
        const float* wvsF = reinterpret_cast<const float*>(wvs4);
        #pragma unroll
        for (int r = 0; r < 8; ++r) {
            const int k = s * 8 + r;
            float c0 = wcsF[r * 768 + 3 * tid];
            float c1 = wcsF[r * 768 + 3 * tid + 1];
            float c2 = wcsF[r * 768 + 3 * tid + 2];
            float vv = wvsF[r * 256 + tid];
            float4 hA = h4v[k * 2], hB = h4v[k * 2 + 1];   // uniform -> broadcast
            float hb[8] = {hA.x, hA.y, hA.z, hA.w, hB.x, hB.y, hB.z, hB.w};
            #pragma unroll
            for (int b = 0; b < NB; ++b) {
                acc[0][b] = fmaf(hb[b], c0, acc[0][b]);
                acc[1][b] = fmaf(hb[b], c1, acc[1][b]);
                acc[2][b] = fmaf(hb[b], c2, acc[2][b]);
                acc[3][b] = fmaf(hb[b], vv, acc[3][b]);
            }
        }
    }

    // epilogue: this thread owns point pt for all 8 batches
    const float factor = 0.5f * DD;
    const float cx = coords0[3 * pt], cy = coords0[3 * pt + 1], cz = coords0[3 * pt + 2];
    const float bx = bc[3 * pt], by = bc[3 * pt + 1], bz = bc[3 * pt + 2];
    const float v0 = values0[pt], bvv = bv[pt];
    #pragma unroll
    for (int b = 0; b < NB; ++b) {
        float px = factor * (cx + (acc[0][b] + bx)) + factor;
        float py = factor * (cy + (acc[1][b] + by)) + factor;
        float pz = factor * (cz + (acc[2][b] + bz)) + factor;
        float val = fmaxf(v0 + (acc[3][b] + bvv), 0.f);
        posval[(size_t)b * NV + pt] = make_float4(px, py, pz, val);
    }
}

// ----------------------------- binning helpers -------------------------------------
// brick(bx,by,bz) covers voxels x:[bx*32,+32) y:[by*8,+8) z:[bz*4,+4); bin=(bz*16+by)*4+bx
__device__ __forceinline__ bool point_base(float4 q, int& ix, int& iy, int& iz) {
    if (q.w == 0.f) return false;                   // relu-zeroed: no contribution
    ix = (int)floorf(q.x); iy = (int)floorf(q.y); iz = (int)floorf(q.z);
    return ix >= -1 && ix <= 127 && iy >= -1 && iy <= 127 && iz >= -1 && iz <= 127;
}

__device__ __forceinline__ void brick_span(int ix, int iy, int iz,
                                           int& bx0, int& bx1, int& by0, int& by1,
                                           int& bz0, int& bz1) {
    bx0 = (ix < 0 ? 0 : ix) >> 5;  bx1 = (ix + 1 > 127 ? 127 : ix + 1) >> 5;
    by0 = (iy < 0 ? 0 : iy) >> 3;  by1 = (iy + 1 > 127 ? 127 : iy + 1) >> 3;
    bz0 = (iz < 0 ? 0 : iz) >> 2;  bz1 = (iz + 1 > 127 ? 127 : iz + 1) >> 2;
}

// --------------- k_count: LDS histogram of (duplicated) entries per brick ----------
__global__ __launch_bounds__(256) void k_count(const float4* __restrict__ posval,
                                               unsigned* __restrict__ binCount)
{
    __shared__ unsigned hist[NBIN];   // 8 KB
    const int tid = threadIdx.x;
    const int batch = blockIdx.x >> 5;
    const size_t base = (size_t)batch * NV + (blockIdx.x & 31) * 2048;
    for (int i = tid; i < NBIN; i += 256) hist[i] = 0;
    __syncthreads();
    #pragma unroll
    for (int j = 0; j < 8; ++j) {
        float4 q = posval[base + j * 256 + tid];
        int ix, iy, iz;
        if (point_base(q, ix, iy, iz)) {
            int bx0, bx1, by0, by1, bz0, bz1;
            brick_span(ix, iy, iz, bx0, bx1, by0, by1, bz0, bz1);
            for (int bz = bz0; bz <= bz1; ++bz)
                for (int by = by0; by <= by1; ++by)
                    for (int bx = bx0; bx <= bx1; ++bx)
                        atomicAdd(&hist[(bz * 16 + by) * 4 + bx], 1u);
        }
    }
    __syncthreads();
    for (int i = tid; i < NBIN; i += 256) {
        unsigned c = hist[i];
        if (c) atomicAdd(&binCount[batch * NBIN + i], c);
    }
}

// --------------- k_scan: exclusive scan over 16384 bins (single block) -------------
__global__ __launch_bounds__(1024) void k_scan(const unsigned* __restrict__ cnt,
                                               unsigned* __restrict__ start,
                                               unsigned* __restrict__ cursor)
{
    __shared__ unsigned partial[1024];
    const int t = threadIdx.x;
    const int base = t * 16;
    unsigned s = 0;
    #pragma unroll
    for (int j = 0; j < 16; ++j) s += cnt[base + j];
    partial[t] = s;
    __syncthreads();
    for (int off = 1; off < 1024; off <<= 1) {
        unsigned mine = partial[t];
        unsigned add = (t >= off) ? partial[t - off] : 0u;
        __syncthreads();
        partial[t] = mine + add;
        __syncthreads();
    }
    unsigned run = (t > 0) ? partial[t - 1] : 0u;
    #pragma unroll
    for (int j = 0; j < 16; ++j) {
        start[base + j] = run;
        cursor[base + j] = run;
        run += cnt[base + j];
    }
    if (t == 1023) start[NBIN_TOT] = partial[1023];
}

// -------- k_scatter: copy each point into every touched brick's contiguous range ----
__global__ __launch_bounds__(256) void k_scatter(const float4* __restrict__ posval,
                                                 unsigned* __restrict__ binCursor,
                                                 float4* __restrict__ sorted)
{
    __shared__ unsigned hist[NBIN];    // counts, then reused as local cursor
    __shared__ unsigned bbase[NBIN];
    const int tid = threadIdx.x;
    const int batch = blockIdx.x >> 5;
    const size_t base = (size_t)batch * NV + (blockIdx.x & 31) * 2048;
    for (int i = tid; i < NBIN; i += 256) hist[i] = 0;
    __syncthreads();

    float4 q[8];
    #pragma unroll
    for (int j = 0; j < 8; ++j) {
        q[j] = posval[base + j * 256 + tid];
        int ix, iy, iz;
        if (point_base(q[j], ix, iy, iz)) {
            int bx0, bx1, by0, by1, bz0, bz1;
            brick_span(ix, iy, iz, bx0, bx1, by0, by1, bz0, bz1);
            for (int bz = bz0; bz <= bz1; ++bz)
                for (int by = by0; by <= by1; ++by)
                    for (int bx = bx0; bx <= bx1; ++bx)
                        atomicAdd(&hist[(bz * 16 + by) * 4 + bx], 1u);
        }
    }
    __syncthreads();
    for (int i = tid; i < NBIN; i += 256) {
        unsigned c = hist[i];
        bbase[i] = c ? atomicAdd(&binCursor[batch * NBIN + i], c) : 0u;
    }
    __syncthreads();
    for (int i = tid; i < NBIN; i += 256) hist[i] = 0;   // reuse as local cursor
    __syncthreads();
    #pragma unroll
    for (int j = 0; j < 8; ++j) {
        int ix, iy, iz;
        if (point_base(q[j], ix, iy, iz)) {
            int bx0, bx1, by0, by1, bz0, bz1;
            brick_span(ix, iy, iz, bx0, bx1, by0, by1, bz0, bz1);
            for (int bz = bz0; bz <= bz1; ++bz)
                for (int by = by0; by <= by1; ++by)
                    for (int bx = bx0; bx <= bx1; ++bx) {
                        int bin = (bz * 16 + by) * 4 + bx;
                        unsigned r = atomicAdd(&hist[bin], 1u);
                        sorted[bbase[bin] + r] = q[j];
                    }
        }
    }
}

// -------- k_binsplat: one block per 32x8x4 brick; exact list; LDS accumulate -------
__global__ __launch_bounds__(256) void k_binsplat(const float4* __restrict__ sorted,
                                                  const unsigned* __restrict__ binStart,
                                                  float* __restrict__ grid)
{
    __shared__ float brick[4 * 8 * 32];   // 4 KB
    const int tid = threadIdx.x;
    const int bid = blockIdx.x;           // [batch][bz 0..31][by 0..15][bx 0..3]
    const int bx = bid & 3;
    const int by = (bid >> 2) & 15;
    const int bz = (bid >> 6) & 31;
    const int batch = bid >> 11;
    const int x0 = bx << 5, y0 = by << 3, z0 = bz << 2;

    const unsigned s = binStart[bid], e = binStart[bid + 1];

    const int vx4 = tid & 7, cy = (tid >> 3) & 7, cz = tid >> 6;
    const size_t o = (size_t)batch * D3 + (size_t)(z0 + cz) * (DD * DD)
                   + (size_t)(y0 + cy) * DD + x0 + vx4 * 4;

    if (s == e) {   // empty brick: pure zero-write (replaces global memset)
        *reinterpret_cast<float4*>(grid + o) = make_float4(0.f, 0.f, 0.f, 0.f);
        return;
    }

    for (int i = tid; i < 1024; i += 256) brick[i] = 0.f;
    __syncthreads();

    for (unsigned i = s + tid; i < e; i += 256) {
        float4 q = sorted[i];
        float fx = floorf(q.x), fy = floorf(q.y), fz = floorf(q.z);
        int vx = (int)fx - x0, vy = (int)fy - y0, vz = (int)fz - z0;
        float gx = q.x - fx, gy = q.y - fy, gz = q.z - fz;
        float wx0 = 1.f - gx, wy0 = 1.f - gy, wz0 = 1.f - gz;
        #pragma unroll
        for (int oz = 0; oz < 2; ++oz)
        #pragma unroll
        for (int oy = 0; oy < 2; ++oy)
        #pragma unroll
        for (int ox = 0; ox < 2; ++ox) {
            int cxx = vx + ox, cyy = vy + oy, czz = vz + oz;
            if ((unsigned)cxx < 32u && (unsigned)cyy < 8u && (unsigned)czz < 4u) {
                float w = ((ox ? gx : wx0) * (oy ? gy : wy0)) * (oz ? gz : wz0);
                atomicAdd(&brick[(czz * 8 + cyy) * 32 + cxx], q.w * w);
            }
        }
    }
    __syncthreads();

    *reinterpret_cast<float4*>(grid + o) =
        *reinterpret_cast<const float4*>(&brick[(cz * 8 + cy) * 32 + vx4 * 4]);
}

// ------------------------- separable 7-tap gaussian blur (pencil) ------------------
__global__ __launch_bounds__(256) void k_blur(const float* __restrict__ in,
                                              float* __restrict__ out, int shift)
{
    const long i = (long)blockIdx.x * 256 + threadIdx.x;
    const int p = (int)((i >> shift) & (DD - 1));

    const double e1 = 0.6065306597126334, e2 = 0.1353352832366127, e3 = 0.011108996538242306;
    const double s = 1.0 + 2.0 * (e1 + e2 + e3);
    const float kw[7] = {(float)(e3 / s), (float)(e2 / s), (float)(e1 / s), (float)(1.0 / s),
                         (float)(e1 / s), (float)(e2 / s), (float)(e3 / s)};

    float acc = 0.f;
    #pragma unroll
    for (int j = -3; j <= 3; ++j) {
        int q = p + j;
        if (q >= 0 && q < DD)
            acc = fmaf(kw[j + 3], in[i + ((long)j << shift)], acc);
    }
    out[i] = acc;
}

// ------------------ fused y+x blur: 32-row y-strips per (batch, z) -----------------
__global__ __launch_bounds__(256) void k_blur_yx(const float* __restrict__ in,
                                                 float* __restrict__ out)
{
    __shared__ float sin_[38 * 128];   // 19 KB: 32 rows + 3 halo each side
    __shared__ float sy[32 * 128];     // 16 KB: y-blur result

    const double e1 = 0.6065306597126334, e2 = 0.1353352832366127, e3 = 0.011108996538242306;
    const double ss = 1.0 + 2.0 * (e1 + e2 + e3);
    const float kw[7] = {(float)(e3 / ss), (float)(e2 / ss), (float)(e1 / ss), (float)(1.0 / ss),
                         (float)(e1 / ss), (float)(e2 / ss), (float)(e3 / ss)};

    const int tid = threadIdx.x;
    const int bid = blockIdx.x;            // [batch][z][ytile]
    const int ytile = bid & 3;
    const int z = (bid >> 2) & 127;
    const int batch = bid >> 9;
    const int y0 = ytile << 5;
    const size_t slab = (size_t)batch * D3 + (size_t)z * (DD * DD);

    for (int i = tid; i < 38 * 128; i += 256) {
        int row = i >> 7, xx = i & 127;
        int gy = y0 + row - 3;
        sin_[i] = (gy >= 0 && gy < DD) ? in[slab + (size_t)gy * DD + xx] : 0.f;
    }
    __syncthreads();

    for (int i = tid; i < 32 * 128; i += 256) {
        int r = i >> 7, xx = i & 127;
        float acc = 0.f;
        #pragma unroll
        for (int j = 0; j < 7; ++j)
            acc = fmaf(kw[j], sin_[(r + j) * 128 + xx], acc);
        sy[i] = acc;
    }
    __syncthreads();

    for (int i = tid; i < 32 * 128; i += 256) {
        int r = i >> 7, xx = i & 127;
        float acc = 0.f;
        #pragma unroll
        for (int j = -3; j <= 3; ++j) {
            int qx = xx + j;
            if (qx >= 0 && qx < DD)
                acc = fmaf(kw[j + 3], sy[r * 128 + qx], acc);
        }
        out[slab + (size_t)(y0 + r) * DD + xx] = acc;
    }
}

extern "C" void kernel_launch(void* const* d_in, const int* in_sizes, int n_in,
                              void* d_out, int out_size, void* d_ws, size_t ws_size,
                              hipStream_t stream) {
    const float* x   = (const float*)d_in[0];
    const float* w0  = (const float*)d_in[1];
    const float* b0  = (const float*)d_in[2];
    const float* w1  = (const float*)d_in[3];
    const float* b1  = (const float*)d_in[4];
    const float* w2  = (const float*)d_in[5];
    const float* b2  = (const float*)d_in[6];
    const float* w3  = (const float*)d_in[7];
    const float* b3  = (const float*)d_in[8];
    const float* w4  = (const float*)d_in[9];
    const float* b4  = (const float*)d_in[10];
    const float* wc  = (const float*)d_in[11];
    const float* bc  = (const float*)d_in[12];
    const float* wv  = (const float*)d_in[13];
    const float* bv  = (const float*)d_in[14];
    const float* c0  = (const float*)d_in[15];
    const float* v0  = (const float*)d_in[16];

    float* out = (float*)d_out;
    // d_out staging (consumed before k_binsplat rewrites d_out as the raw grid):
    float4* posval = (float4*)d_out;                  // [NB][NV] float4 = 8 MiB
    float* h4 = out + 4 * 1024 * 1024;                // at +16 MiB
    float* hA = h4 + 2048;
    float* hB = hA + 2048;
    // ws staging (consumed before blur-z rewrites ws with the 64MB grid):
    float4* sorted = (float4*)d_ws;                   // ~6 MiB actual
    unsigned* binCount  = (unsigned*)((char*)d_ws + (48u << 20));
    unsigned* binStart  = binCount + NBIN_TOT;        // NBIN_TOT+1 entries
    unsigned* binCursor = binStart + NBIN_TOT + 1;
    unsigned* bar       = binCursor + NBIN_TOT;       // 8 barrier counters

    hipMemsetAsync(binCount, 0, NBIN_TOT * sizeof(unsigned), stream);
    hipMemsetAsync(bar, 0, 8 * sizeof(unsigned), stream);

    // fused SIREN MLP (4 blocks, spin-barrier between layers)
    k_mlp_fused<<<4, 256, 0, stream>>>(x, w0, b0, w1, b1, w2, b2, w3, b3, w4, b4,
                                       hA, hB, h4, bar);

    k_heads<<<NV / 256, 256, 0, stream>>>(h4, wc, bc, wv, bv, c0, v0, posval);

    k_count<<<256, 256, 0, stream>>>(posval, binCount);
    k_scan<<<1, 1024, 0, stream>>>(binCount, binStart, binCursor);
    k_scatter<<<256, 256, 0, stream>>>(posval, binCursor, sorted);
    k_binsplat<<<NBIN_TOT, 256, 0, stream>>>(sorted, binStart, out);   // raw grid -> d_out

    const int nblk = (NB * D3) / 256;   // 65536
    k_blur<<<nblk, 256, 0, stream>>>(out, (float*)d_ws, 14);           // z: d_out -> ws
    k_blur_yx<<<NB * 512, 256, 0, stream>>>((float*)d_ws, out);        // y+x: ws -> d_out
}

// Round 10
// 377.909 us; speedup vs baseline: 1.1049x; 1.1049x over previous
//
#include <hip/hip_runtime.h>
#include <hip/hip_bf16.h>

#define DD 128
#define D3 (DD*DD*DD)      // 2097152
#define NB 8               // batch
#define NV 65536           // points
#define HID 256
#define LAT 128

// bricks: 32x8x4 voxels -> 4 x 16 x 32 = 2048 per batch, 16384 total
#define NBIN 2048
#define NBIN_TOT (NBIN*NB) // 16384

// round-to-nearest-even f32 -> bf16, returned as the (exactly representable) f32 value
__device__ __forceinline__ float rbf(float x) {
    unsigned u = __float_as_uint(x);
    unsigned r = (u + 0x7fffu + ((u >> 16) & 1u)) & 0xFFFF0000u;
    return __uint_as_float(r);
}

// ====== heads + in-block MLP ======
// Phase A: every block redundantly computes the 5-layer SIREN MLP (1.125 MB of
//          weights, L2-resident after first touch; thread = output column,
//          serial K, LDS [k][b] handoff). ~12 us, paid concurrently by all CUs.
// Phase B: LDS-staged streaming GEMV over wc/wv (268 MB, coalesced float4
//          staging, issue-early/write-late). thread = 1 point, all 8 batches.
__global__ __launch_bounds__(256) void k_heads(
    const float* __restrict__ x,
    const float* __restrict__ w0, const float* __restrict__ b0,
    const float* __restrict__ w1, const float* __restrict__ b1,
    const float* __restrict__ w2, const float* __restrict__ b2,
    const float* __restrict__ w3, const float* __restrict__ b3,
    const float* __restrict__ w4, const float* __restrict__ b4,
    const float* __restrict__ wc, const float* __restrict__ bc,
    const float* __restrict__ wv, const float* __restrict__ bv,
    const float* __restrict__ coords0, const float* __restrict__ values0,
    float4* __restrict__ posval)
{
    __shared__ float  xsT[LAT * NB];       // 4 KB  [k][b] of x (bf16-rounded)
    __shared__ float  hbA[HID * NB];       // 8 KB  [k][b] ping
    __shared__ float  hbB[HID * NB];       // 8 KB  [k][b] pong
    __shared__ float  hsT[HID * NB];       // 8 KB  [k][b] final h4
    __shared__ float4 wcs4[8 * 192];       // 24 KB: 8 k-rows x 768 floats
    __shared__ float4 wvs4[8 * 64];        // 8 KB:  8 k-rows x 256 floats

    const int tid = threadIdx.x;
    const int blk = blockIdx.x;
    const int pt  = blk * 256 + tid;       // this thread's point

    const float4* wc4 = reinterpret_cast<const float4*>(wc);
    const float4* wv4 = reinterpret_cast<const float4*>(wv);

    // per-thread stage-load slots (wave-aligned: 64 consecutive float4 per instr)
    size_t wbase[6]; int lwc[6];
    #pragma unroll
    for (int j = 0; j < 6; ++j) {
        int idx = j * 256 + tid;
        int row = idx / 192, col = idx - row * 192;       // 192 float4 per wc row-slice
        wbase[j] = (size_t)row * 49152 + (size_t)blk * 192 + col;   // 49152 f4/row
        lwc[j] = idx;
    }
    size_t vbase[2]; int lwv[2];
    #pragma unroll
    for (int j = 0; j < 2; ++j) {
        int idx = j * 256 + tid;
        int row = idx >> 6, col = idx & 63;               // 64 float4 per wv row-slice
        vbase[j] = (size_t)row * 16384 + (size_t)blk * 64 + col;    // 16384 f4/row
        lwv[j] = idx;
    }

    // issue stage-0 loads now; they complete while the MLP runs
    float4 Rw0, Rw1, Rw2, Rw3, Rw4, Rw5, Rv0, Rv1;
    Rw0 = wc4[wbase[0]]; Rw1 = wc4[wbase[1]]; Rw2 = wc4[wbase[2]];
    Rw3 = wc4[wbase[3]]; Rw4 = wc4[wbase[4]]; Rw5 = wc4[wbase[5]];
    Rv0 = wv4[vbase[0]]; Rv1 = wv4[vbase[1]];

    // ---------------- Phase A: in-block MLP ----------------
    // x -> xsT[k][b]
    for (int i = tid; i < NB * LAT; i += 256) {
        int b = i >> 7, k = i & 127;
        xsT[k * 8 + b] = rbf(x[i]);
    }
    __syncthreads();

    float a[NB];
    const float4* xsp = reinterpret_cast<const float4*>(xsT);

    // layer 0: h = rbf(sin(rbf(30*rbf(rbf(s)+b0))))
    #pragma unroll
    for (int b = 0; b < NB; ++b) a[b] = 0.f;
    #pragma unroll 8
    for (int k = 0; k < LAT; ++k) {
        float wk = rbf(w0[k * HID + tid]);           // 1KB/row, all blocks share -> L2
        float4 hA_ = xsp[k * 2], hB_ = xsp[k * 2 + 1];
        float hb[8] = {hA_.x, hA_.y, hA_.z, hA_.w, hB_.x, hB_.y, hB_.z, hB_.w};
        #pragma unroll
        for (int b = 0; b < NB; ++b) a[b] = fmaf(hb[b], wk, a[b]);
    }
    {
        float bb = rbf(b0[tid]);
        #pragma unroll
        for (int b = 0; b < NB; ++b) {
            float t = rbf(a[b]);
            t = rbf(t + bb);
            t = rbf(30.0f * t);
            hbA[tid * 8 + b] = rbf(sinf(t));
        }
    }
    __syncthreads();

    // layers 1..3: h = rbf(sin(rbf(h + rbf(rbf(s)+b))))
    {
        const float* Ws[3] = {w1, w2, w3};
        const float* Bs[3] = {b1, b2, b3};
        float* cur = hbA;
        float* nxt = hbB;
        for (int L = 0; L < 3; ++L) {
            const float* w = Ws[L];
            const float4* hp = reinterpret_cast<const float4*>(cur);
            #pragma unroll
            for (int b = 0; b < NB; ++b) a[b] = 0.f;
            #pragma unroll 8
            for (int k = 0; k < HID; ++k) {
                float wk = rbf(w[k * HID + tid]);
                float4 hA_ = hp[k * 2], hB_ = hp[k * 2 + 1];
                float hb[8] = {hA_.x, hA_.y, hA_.z, hA_.w, hB_.x, hB_.y, hB_.z, hB_.w};
                #pragma unroll
                for (int b = 0; b < NB; ++b) a[b] = fmaf(hb[b], wk, a[b]);
            }
            float bb = rbf(Bs[L][tid]);
            #pragma unroll
            for (int b = 0; b < NB; ++b) {
                float t = rbf(a[b]);
                t = rbf(t + bb);
                float r = rbf(cur[tid * 8 + b] + t);
                nxt[tid * 8 + b] = rbf(sinf(r));
            }
            __syncthreads();
            float* tmp = cur; cur = nxt; nxt = tmp;
        }
        // layer 4 (linear): h4 = rbf(rbf(s)+b4) -> hsT[k][b]
        const float4* hp = reinterpret_cast<const float4*>(cur);
        #pragma unroll
        for (int b = 0; b < NB; ++b) a[b] = 0.f;
        #pragma unroll 8
        for (int k = 0; k < HID; ++k) {
            float wk = rbf(w4[k * HID + tid]);
            float4 hA_ = hp[k * 2], hB_ = hp[k * 2 + 1];
            float hb[8] = {hA_.x, hA_.y, hA_.z, hA_.w, hB_.x, hB_.y, hB_.z, hB_.w};
            #pragma unroll
            for (int b = 0; b < NB; ++b) a[b] = fmaf(hb[b], wk, a[b]);
        }
        float bb = rbf(b4[tid]);
        #pragma unroll
        for (int b = 0; b < NB; ++b) {
            float t = rbf(a[b]);
            hsT[tid * 8 + b] = rbf(t + bb);
        }
    }
    // (visibility of hsT covered by the __syncthreads at top of stage loop)

    // ---------------- Phase B: streaming staged GEMV ----------------
    float acc[4][8];                       // [x,y,z,val][batch]
    #pragma unroll
    for (int c = 0; c < 4; ++c)
        #pragma unroll
        for (int b = 0; b < NB; ++b) acc[c][b] = 0.f;

    const float4* h4v = reinterpret_cast<const float4*>(hsT);

    for (int s = 0; s < 32; ++s) {
        __syncthreads();                   // stage s-1 consumers done (also hsT publish)
        wcs4[lwc[0]] = Rw0; wcs4[lwc[1]] = Rw1; wcs4[lwc[2]] = Rw2;
        wcs4[lwc[3]] = Rw3; wcs4[lwc[4]] = Rw4; wcs4[lwc[5]] = Rw5;
        wvs4[lwv[0]] = Rv0; wvs4[lwv[1]] = Rv1;
        if (s < 31) {                      // issue next stage early (hidden under FMAs)
            size_t ow = (size_t)(s + 1) * 8 * 49152;
            size_t ov = (size_t)(s + 1) * 8 * 16384;
            Rw0 = wc4[wbase[0] + ow]; Rw1 = wc4[wbase[1] + ow]; Rw2 = wc4[wbase[2] + ow];
            Rw3 = wc4[wbase[3] + ow]; Rw4 = wc4[wbase[4] + ow]; Rw5 = wc4[wbase[5] + ow];
            Rv0 = wv4[vbase[0] + ov]; Rv1 = wv4[vbase[1] + ov];
        }
        __syncthreads();                   // stage s staged

        const float* wcsF = reinterpret_cast<const float*>(wcs4);
        const float* wvsF = reinterpret_cast<const float*>(wvs4);
        #pragma unroll
        for (int r = 0; r < 8; ++r) {
            const int k = s * 8 + r;
            float c0 = wcsF[r * 768 + 3 * tid];
            float c1 = wcsF[r * 768 + 3 * tid + 1];
            float c2 = wcsF[r * 768 + 3 * tid + 2];
            float vv = wvsF[r * 256 + tid];
            float4 hA_ = h4v[k * 2], hB_ = h4v[k * 2 + 1];   // uniform -> broadcast
            float hb[8] = {hA_.x, hA_.y, hA_.z, hA_.w, hB_.x, hB_.y, hB_.z, hB_.w};
            #pragma unroll
            for (int b = 0; b < NB; ++b) {
                acc[0][b] = fmaf(hb[b], c0, acc[0][b]);
                acc[1][b] = fmaf(hb[b], c1, acc[1][b]);
                acc[2][b] = fmaf(hb[b], c2, acc[2][b]);
                acc[3][b] = fmaf(hb[b], vv, acc[3][b]);
            }
        }
    }

    // epilogue: this thread owns point pt for all 8 batches
    const float factor = 0.5f * DD;
    const float cx = coords0[3 * pt], cy = coords0[3 * pt + 1], cz = coords0[3 * pt + 2];
    const float bx = bc[3 * pt], by = bc[3 * pt + 1], bz = bc[3 * pt + 2];
    const float v0 = values0[pt], bvv = bv[pt];
    #pragma unroll
    for (int b = 0; b < NB; ++b) {
        float px = factor * (cx + (acc[0][b] + bx)) + factor;
        float py = factor * (cy + (acc[1][b] + by)) + factor;
        float pz = factor * (cz + (acc[2][b] + bz)) + factor;
        float val = fmaxf(v0 + (acc[3][b] + bvv), 0.f);
        posval[(size_t)b * NV + pt] = make_float4(px, py, pz, val);
    }
}

// ----------------------------- binning helpers -------------------------------------
// brick(bx,by,bz) covers voxels x:[bx*32,+32) y:[by*8,+8) z:[bz*4,+4); bin=(bz*16+by)*4+bx
__device__ __forceinline__ bool point_base(float4 q, int& ix, int& iy, int& iz) {
    if (q.w == 0.f) return false;                   // relu-zeroed: no contribution
    ix = (int)floorf(q.x); iy = (int)floorf(q.y); iz = (int)floorf(q.z);
    return ix >= -1 && ix <= 127 && iy >= -1 && iy <= 127 && iz >= -1 && iz <= 127;
}

__device__ __forceinline__ void brick_span(int ix, int iy, int iz,
                                           int& bx0, int& bx1, int& by0, int& by1,
                                           int& bz0, int& bz1) {
    bx0 = (ix < 0 ? 0 : ix) >> 5;  bx1 = (ix + 1 > 127 ? 127 : ix + 1) >> 5;
    by0 = (iy < 0 ? 0 : iy) >> 3;  by1 = (iy + 1 > 127 ? 127 : iy + 1) >> 3;
    bz0 = (iz < 0 ? 0 : iz) >> 2;  bz1 = (iz + 1 > 127 ? 127 : iz + 1) >> 2;
}

// --------------- k_count: LDS histogram of (duplicated) entries per brick ----------
__global__ __launch_bounds__(256) void k_count(const float4* __restrict__ posval,
                                               unsigned* __restrict__ binCount)
{
    __shared__ unsigned hist[NBIN];   // 8 KB
    const int tid = threadIdx.x;
    const int batch = blockIdx.x >> 5;
    const size_t base = (size_t)batch * NV + (blockIdx.x & 31) * 2048;
    for (int i = tid; i < NBIN; i += 256) hist[i] = 0;
    __syncthreads();
    #pragma unroll
    for (int j = 0; j < 8; ++j) {
        float4 q = posval[base + j * 256 + tid];
        int ix, iy, iz;
        if (point_base(q, ix, iy, iz)) {
            int bx0, bx1, by0, by1, bz0, bz1;
            brick_span(ix, iy, iz, bx0, bx1, by0, by1, bz0, bz1);
            for (int bz = bz0; bz <= bz1; ++bz)
                for (int by = by0; by <= by1; ++by)
                    for (int bx = bx0; bx <= bx1; ++bx)
                        atomicAdd(&hist[(bz * 16 + by) * 4 + bx], 1u);
        }
    }
    __syncthreads();
    for (int i = tid; i < NBIN; i += 256) {
        unsigned c = hist[i];
        if (c) atomicAdd(&binCount[batch * NBIN + i], c);
    }
}

// --------------- k_scan: exclusive scan over 16384 bins (single block) -------------
__global__ __launch_bounds__(1024) void k_scan(const unsigned* __restrict__ cnt,
                                               unsigned* __restrict__ start,
                                               unsigned* __restrict__ cursor)
{
    __shared__ unsigned partial[1024];
    const int t = threadIdx.x;
    const int base = t * 16;
    unsigned s = 0;
    #pragma unroll
    for (int j = 0; j < 16; ++j) s += cnt[base + j];
    partial[t] = s;
    __syncthreads();
    for (int off = 1; off < 1024; off <<= 1) {
        unsigned mine = partial[t];
        unsigned add = (t >= off) ? partial[t - off] : 0u;
        __syncthreads();
        partial[t] = mine + add;
        __syncthreads();
    }
    unsigned run = (t > 0) ? partial[t - 1] : 0u;
    #pragma unroll
    for (int j = 0; j < 16; ++j) {
        start[base + j] = run;
        cursor[base + j] = run;
        run += cnt[base + j];
    }
    if (t == 1023) start[NBIN_TOT] = partial[1023];
}

// -------- k_scatter: copy each point into every touched brick's contiguous range ----
__global__ __launch_bounds__(256) void k_scatter(const float4* __restrict__ posval,
                                                 unsigned* __restrict__ binCursor,
                                                 float4* __restrict__ sorted)
{
    __shared__ unsigned hist[NBIN];    // counts, then reused as local cursor
    __shared__ unsigned bbase[NBIN];
    const int tid = threadIdx.x;
    const int batch = blockIdx.x >> 5;
    const size_t base = (size_t)batch * NV + (blockIdx.x & 31) * 2048;
    for (int i = tid; i < NBIN; i += 256) hist[i] = 0;
    __syncthreads();

    float4 q[8];
    #pragma unroll
    for (int j = 0; j < 8; ++j) {
        q[j] = posval[base + j * 256 + tid];
        int ix, iy, iz;
        if (point_base(q[j], ix, iy, iz)) {
            int bx0, bx1, by0, by1, bz0, bz1;
            brick_span(ix, iy, iz, bx0, bx1, by0, by1, bz0, bz1);
            for (int bz = bz0; bz <= bz1; ++bz)
                for (int by = by0; by <= by1; ++by)
                    for (int bx = bx0; bx <= bx1; ++bx)
                        atomicAdd(&hist[(bz * 16 + by) * 4 + bx], 1u);
        }
    }
    __syncthreads();
    for (int i = tid; i < NBIN; i += 256) {
        unsigned c = hist[i];
        bbase[i] = c ? atomicAdd(&binCursor[batch * NBIN + i], c) : 0u;
    }
    __syncthreads();
    for (int i = tid; i < NBIN; i += 256) hist[i] = 0;   // reuse as local cursor
    __syncthreads();
    #pragma unroll
    for (int j = 0; j < 8; ++j) {
        int ix, iy, iz;
        if (point_base(q[j], ix, iy, iz)) {
            int bx0, bx1, by0, by1, bz0, bz1;
            brick_span(ix, iy, iz, bx0, bx1, by0, by1, bz0, bz1);
            for (int bz = bz0; bz <= bz1; ++bz)
                for (int by = by0; by <= by1; ++by)
                    for (int bx = bx0; bx <= bx1; ++bx) {
                        int bin = (bz * 16 + by) * 4 + bx;
                        unsigned r = atomicAdd(&hist[bin], 1u);
                        sorted[bbase[bin] + r] = q[j];
                    }
        }
    }
}

// -------- k_binsplat: one block per 32x8x4 brick; exact list; LDS accumulate -------
__global__ __launch_bounds__(256) void k_binsplat(const float4* __restrict__ sorted,
                                                  const unsigned* __restrict__ binStart,
                                                  float* __restrict__ grid)
{
    __shared__ float brick[4 * 8 * 32];   // 4 KB
    const int tid = threadIdx.x;
    const int bid = blockIdx.x;           // [batch][bz 0..31][by 0..15][bx 0..3]
    const int bx = bid & 3;
    const int by = (bid >> 2) & 15;
    const int bz = (bid >> 6) & 31;
    const int batch = bid >> 11;
    const int x0 = bx << 5, y0 = by << 3, z0 = bz << 2;

    const unsigned s = binStart[bid], e = binStart[bid + 1];

    const int vx4 = tid & 7, cy = (tid >> 3) & 7, cz = tid >> 6;
    const size_t o = (size_t)batch * D3 + (size_t)(z0 + cz) * (DD * DD)
                   + (size_t)(y0 + cy) * DD + x0 + vx4 * 4;

    if (s == e) {   // empty brick: pure zero-write (replaces global memset)
        *reinterpret_cast<float4*>(grid + o) = make_float4(0.f, 0.f, 0.f, 0.f);
        return;
    }

    for (int i = tid; i < 1024; i += 256) brick[i] = 0.f;
    __syncthreads();

    for (unsigned i = s + tid; i < e; i += 256) {
        float4 q = sorted[i];
        float fx = floorf(q.x), fy = floorf(q.y), fz = floorf(q.z);
        int vx = (int)fx - x0, vy = (int)fy - y0, vz = (int)fz - z0;
        float gx = q.x - fx, gy = q.y - fy, gz = q.z - fz;
        float wx0 = 1.f - gx, wy0 = 1.f - gy, wz0 = 1.f - gz;
        #pragma unroll
        for (int oz = 0; oz < 2; ++oz)
        #pragma unroll
        for (int oy = 0; oy < 2; ++oy)
        #pragma unroll
        for (int ox = 0; ox < 2; ++ox) {
            int cxx = vx + ox, cyy = vy + oy, czz = vz + oz;
            if ((unsigned)cxx < 32u && (unsigned)cyy < 8u && (unsigned)czz < 4u) {
                float w = ((ox ? gx : wx0) * (oy ? gy : wy0)) * (oz ? gz : wz0);
                atomicAdd(&brick[(czz * 8 + cyy) * 32 + cxx], q.w * w);
            }
        }
    }
    __syncthreads();

    *reinterpret_cast<float4*>(grid + o) =
        *reinterpret_cast<const float4*>(&brick[(cz * 8 + cy) * 32 + vx4 * 4]);
}

// ------------------------- separable 7-tap gaussian blur (pencil) ------------------
__global__ __launch_bounds__(256) void k_blur(const float* __restrict__ in,
                                              float* __restrict__ out, int shift)
{
    const long i = (long)blockIdx.x * 256 + threadIdx.x;
    const int p = (int)((i >> shift) & (DD - 1));

    const double e1 = 0.6065306597126334, e2 = 0.1353352832366127, e3 = 0.011108996538242306;
    const double s = 1.0 + 2.0 * (e1 + e2 + e3);
    const float kw[7] = {(float)(e3 / s), (float)(e2 / s), (float)(e1 / s), (float)(1.0 / s),
                         (float)(e1 / s), (float)(e2 / s), (float)(e3 / s)};

    float acc = 0.f;
    #pragma unroll
    for (int j = -3; j <= 3; ++j) {
        int q = p + j;
        if (q >= 0 && q < DD)
            acc = fmaf(kw[j + 3], in[i + ((long)j << shift)], acc);
    }
    out[i] = acc;
}

// ------------------ fused y+x blur: 32-row y-strips per (batch, z) -----------------
__global__ __launch_bounds__(256) void k_blur_yx(const float* __restrict__ in,
                                                 float* __restrict__ out)
{
    __shared__ float sin_[38 * 128];   // 19 KB: 32 rows + 3 halo each side
    __shared__ float sy[32 * 128];     // 16 KB: y-blur result

    const double e1 = 0.6065306597126334, e2 = 0.1353352832366127, e3 = 0.011108996538242306;
    const double ss = 1.0 + 2.0 * (e1 + e2 + e3);
    const float kw[7] = {(float)(e3 / ss), (float)(e2 / ss), (float)(e1 / ss), (float)(1.0 / ss),
                         (float)(e1 / ss), (float)(e2 / ss), (float)(e3 / ss)};

    const int tid = threadIdx.x;
    const int bid = blockIdx.x;            // [batch][z][ytile]
    const int ytile = bid & 3;
    const int z = (bid >> 2) & 127;
    const int batch = bid >> 9;
    const int y0 = ytile << 5;
    const size_t slab = (size_t)batch * D3 + (size_t)z * (DD * DD);

    for (int i = tid; i < 38 * 128; i += 256) {
        int row = i >> 7, xx = i & 127;
        int gy = y0 + row - 3;
        sin_[i] = (gy >= 0 && gy < DD) ? in[slab + (size_t)gy * DD + xx] : 0.f;
    }
    __syncthreads();

    for (int i = tid; i < 32 * 128; i += 256) {
        int r = i >> 7, xx = i & 127;
        float acc = 0.f;
        #pragma unroll
        for (int j = 0; j < 7; ++j)
            acc = fmaf(kw[j], sin_[(r + j) * 128 + xx], acc);
        sy[i] = acc;
    }
    __syncthreads();

    for (int i = tid; i < 32 * 128; i += 256) {
        int r = i >> 7, xx = i & 127;
        float acc = 0.f;
        #pragma unroll
        for (int j = -3; j <= 3; ++j) {
            int qx = xx + j;
            if (qx >= 0 && qx < DD)
                acc = fmaf(kw[j + 3], sy[r * 128 + qx], acc);
        }
        out[slab + (size_t)(y0 + r) * DD + xx] = acc;
    }
}

extern "C" void kernel_launch(void* const* d_in, const int* in_sizes, int n_in,
                              void* d_out, int out_size, void* d_ws, size_t ws_size,
                              hipStream_t stream) {
    const float* x   = (const float*)d_in[0];
    const float* w0  = (const float*)d_in[1];
    const float* b0  = (const float*)d_in[2];
    const float* w1  = (const float*)d_in[3];
    const float* b1  = (const float*)d_in[4];
    const float* w2  = (const float*)d_in[5];
    const float* b2  = (const float*)d_in[6];
    const float* w3  = (const float*)d_in[7];
    const float* b3  = (const float*)d_in[8];
    const float* w4  = (const float*)d_in[9];
    const float* b4  = (const float*)d_in[10];
    const float* wc  = (const float*)d_in[11];
    const float* bc  = (const float*)d_in[12];
    const float* wv  = (const float*)d_in[13];
    const float* bv  = (const float*)d_in[14];
    const float* c0  = (const float*)d_in[15];
    const float* v0  = (const float*)d_in[16];

    float* out = (float*)d_out;
    // d_out staging (consumed before k_binsplat rewrites d_out as the raw grid):
    float4* posval = (float4*)d_out;                  // [NB][NV] float4 = 8 MiB
    // ws staging (consumed before blur-z rewrites ws with the 64MB grid):
    float4* sorted = (float4*)d_ws;                   // ~6 MiB actual
    unsigned* binCount  = (unsigned*)((char*)d_ws + (48u << 20));
    unsigned* binStart  = binCount + NBIN_TOT;        // NBIN_TOT+1 entries
    unsigned* binCursor = binStart + NBIN_TOT + 1;

    hipMemsetAsync(binCount, 0, NBIN_TOT * sizeof(unsigned), stream);

    // heads with in-block MLP (phase A) + streaming GEMV (phase B)
    k_heads<<<NV / 256, 256, 0, stream>>>(x, w0, b0, w1, b1, w2, b2, w3, b3, w4, b4,
                                          wc, bc, wv, bv, c0, v0, posval);

    k_count<<<256, 256, 0, stream>>>(posval, binCount);
    k_scan<<<1, 1024, 0, stream>>>(binCount, binStart, binCursor);
    k_scatter<<<256, 256, 0, stream>>>(posval, binCursor, sorted);
    k_binsplat<<<NBIN_TOT, 256, 0, stream>>>(sorted, binStart, out);   // raw grid -> d_out

    const int nblk = (NB * D3) / 256;   // 65536
    k_blur<<<nblk, 256, 0, stream>>>(out, (float*)d_ws, 14);           // z: d_out -> ws
    k_blur_yx<<<NB * 512, 256, 0, stream>>>((float*)d_ws, out);        // y+x: ws -> d_out
}